// Round 1
// baseline (193.664 us; speedup 1.0000x reference)
//
#include <hip/hip_runtime.h>

#define GRID_S 7
#define NUM_CLASSES 80
#define D_DIM 90
#define LAMBDA_COORD 5.0f
#define LAMBDA_NOOBJ 0.5f
#define EPS_IOU 1e-6f
#define EPS_SQRT 1e-6f

__device__ __forceinline__ float iou_img(float cx1, float cy1, float w1, float h1,
                                         float cx2, float cy2, float w2, float h2) {
    float ixmin = fmaxf(cx1 - w1 * 0.5f, cx2 - w2 * 0.5f);
    float iymin = fmaxf(cy1 - h1 * 0.5f, cy2 - h2 * 0.5f);
    float ixmax = fminf(cx1 + w1 * 0.5f, cx2 + w2 * 0.5f);
    float iymax = fminf(cy1 + h1 * 0.5f, cy2 + h2 * 0.5f);
    float iw = fmaxf(ixmax - ixmin, 0.0f);
    float ih = fmaxf(iymax - iymin, 0.0f);
    float inter = iw * ih;
    float uni = w1 * h1 + w2 * h2 - inter;
    return inter / (uni + EPS_IOU);
}

// ws layout: [0]=n_obj, [1]=sum coord*objf, [2]=conf_sum, [3]=sum class*objf
__global__ __launch_bounds__(256) void yolo_cell_kernel(
        const float* __restrict__ pred, const float* __restrict__ targ,
        float* __restrict__ ws, int ncells) {
    const int cell = blockIdx.x * 256 + threadIdx.x;

    float v_obj = 0.0f, v_coord = 0.0f, v_conf = 0.0f, v_cls = 0.0f;

    if (cell < ncells) {
        const int gxy = cell % (GRID_S * GRID_S);
        const float gy = (float)(gxy / GRID_S);
        const float gx = (float)(gxy % GRID_S);

        const float2* p2 = (const float2*)(pred + (size_t)cell * D_DIM);
        const float2* t2 = (const float2*)(targ + (size_t)cell * D_DIM);

        // pred elements 0..9 : box1 = [0..4], box2 = [5..9]
        float2 pA = p2[0];  // pred0, pred1
        float2 pB = p2[1];  // pred2, pred3
        float2 pC = p2[2];  // pred4, pred5
        float2 pD = p2[3];  // pred6, pred7
        float2 pE = p2[4];  // pred8, pred9
        // target elements 0..4 : tbox = [0..3], obj = [4]
        float2 tA = t2[0];  // t0, t1
        float2 tB = t2[1];  // t2, t3
        float2 tC = t2[2];  // t4 (obj), t5 (unused)

        // class loss: elements 10..89 == float2 indices 5..44
        float cls = 0.0f;
        #pragma unroll
        for (int j = 5; j < 45; ++j) {
            float2 p = p2[j];
            float2 t = t2[j];
            float dx = p.x - t.x;
            float dy = p.y - t.y;
            cls = fmaf(dx, dx, cls);
            cls = fmaf(dy, dy, cls);
        }

        float b1x = pA.x, b1y = pA.y, b1w = pB.x, b1h = pB.y, b1c = pC.x;
        float b2x = pC.y, b2y = pD.x, b2w = pD.y, b2h = pE.x, b2c = pE.y;
        float tbx = tA.x, tby = tA.y, tbw = tB.x, tbh = tB.y;
        float tobj = tC.x;

        const float invS = 1.0f / (float)GRID_S;
        float c1x = (gx + b1x) * invS, c1y = (gy + b1y) * invS;
        float c2x = (gx + b2x) * invS, c2y = (gy + b2y) * invS;
        float ctx = (gx + tbx) * invS, cty = (gy + tby) * invS;

        float iou1 = iou_img(c1x, c1y, b1w, b1h, ctx, cty, tbw, tbh);
        float iou2 = iou_img(c2x, c2y, b2w, b2h, ctx, cty, tbw, tbh);
        bool resp1 = iou1 > iou2;

        float bx = resp1 ? b1x : b2x;
        float by = resp1 ? b1y : b2y;
        float bw = resp1 ? b1w : b2w;
        float bh = resp1 ? b1h : b2h;
        float bc = resp1 ? b1c : b2c;

        bool obj = (tobj == 1.0f);
        float objf = obj ? 1.0f : 0.0f;

        float ddx = bx - tbx, ddy = by - tby;
        float dxy2 = ddx * ddx + ddy * ddy;
        float swpw = sqrtf(fmaxf(bw, EPS_SQRT));
        float swph = sqrtf(fmaxf(bh, EPS_SQRT));
        float swtw = sqrtf(fmaxf(tbw, EPS_SQRT));
        float swth = sqrtf(fmaxf(tbh, EPS_SQRT));
        float dw = swpw - swtw, dh = swph - swth;
        float dwh2 = dw * dw + dh * dh;
        float coord = 0.5f * dxy2 + 0.5f * dwh2;

        float dco = bc - 1.0f;
        float conf_obj = dco * dco;
        float conf_noobj = LAMBDA_NOOBJ * (b1c * b1c + b2c * b2c);

        v_obj = objf;
        v_coord = coord * objf;
        v_conf = obj ? conf_obj : conf_noobj;
        v_cls = cls * (1.0f / (float)NUM_CLASSES) * objf;
    }

    // wave-64 reduction
    #pragma unroll
    for (int off = 32; off > 0; off >>= 1) {
        v_obj   += __shfl_down(v_obj, off, 64);
        v_coord += __shfl_down(v_coord, off, 64);
        v_conf  += __shfl_down(v_conf, off, 64);
        v_cls   += __shfl_down(v_cls, off, 64);
    }

    __shared__ float red[4][4];  // [wave][quantity]
    const int lane = threadIdx.x & 63;
    const int wid = threadIdx.x >> 6;
    if (lane == 0) {
        red[wid][0] = v_obj;
        red[wid][1] = v_coord;
        red[wid][2] = v_conf;
        red[wid][3] = v_cls;
    }
    __syncthreads();
    if (threadIdx.x < 4) {
        // threadIdx.x selects the quantity; sum the 4 waves
        float s = red[0][threadIdx.x] + red[1][threadIdx.x] +
                  red[2][threadIdx.x] + red[3][threadIdx.x];
        atomicAdd(ws + threadIdx.x, s);
    }
}

__global__ void yolo_final_kernel(const float* __restrict__ ws,
                                  float* __restrict__ out, int ncells) {
    float n_obj = ws[0];
    float coord = ws[1];
    float conf = ws[2];
    float cls = ws[3];
    float n_cells = (float)ncells;
    float conf_count = n_obj + 2.0f * (n_cells - n_obj);
    float denom = fmaxf(n_obj, 1.0f);
    out[0] = LAMBDA_COORD * coord / denom + conf / fmaxf(conf_count, 1.0f) + cls / denom;
}

extern "C" void kernel_launch(void* const* d_in, const int* in_sizes, int n_in,
                              void* d_out, int out_size, void* d_ws, size_t ws_size,
                              hipStream_t stream) {
    const float* pred = (const float*)d_in[0];
    const float* targ = (const float*)d_in[1];
    float* ws = (float*)d_ws;
    float* out = (float*)d_out;

    const int ncells = in_sizes[0] / D_DIM;  // B * S * S
    const int blocks = (ncells + 255) / 256;

    hipMemsetAsync(ws, 0, 4 * sizeof(float), stream);
    yolo_cell_kernel<<<blocks, 256, 0, stream>>>(pred, targ, ws, ncells);
    yolo_final_kernel<<<1, 1, 0, stream>>>(ws, out, ncells);
}

// Round 2
// 177.766 us; speedup vs baseline: 1.0894x; 1.0894x over previous
//
#include <hip/hip_runtime.h>

#define GRID_S 7
#define NUM_CLASSES 80
#define D_DIM 90
#define LAMBDA_COORD 5.0f
#define LAMBDA_NOOBJ 0.5f
#define EPS_IOU 1e-6f
#define EPS_SQRT 1e-6f

#define TILE 64
#define TILE_F (TILE * D_DIM)    // 5760 floats per array
#define TILE_F4 (TILE_F / 4)     // 1440 float4

__device__ __forceinline__ float iou_img(float cx1, float cy1, float w1, float h1,
                                         float cx2, float cy2, float w2, float h2) {
    float ixmin = fmaxf(cx1 - w1 * 0.5f, cx2 - w2 * 0.5f);
    float iymin = fmaxf(cy1 - h1 * 0.5f, cy2 - h2 * 0.5f);
    float ixmax = fminf(cx1 + w1 * 0.5f, cx2 + w2 * 0.5f);
    float iymax = fminf(cy1 + h1 * 0.5f, cy2 + h2 * 0.5f);
    float iw = fmaxf(ixmax - ixmin, 0.0f);
    float ih = fmaxf(iymax - iymin, 0.0f);
    float inter = iw * ih;
    float uni = w1 * h1 + w2 * h2 - inter;
    return inter / (uni + EPS_IOU);
}

// ws layout: [0]=n_obj, [1]=sum coord*objf, [2]=conf_sum, [3]=sum class*objf
__global__ __launch_bounds__(256) void yolo_cell_kernel(
        const float* __restrict__ pred, const float* __restrict__ targ,
        float* __restrict__ ws, int ncells) {
    __shared__ float sp[TILE_F];
    __shared__ float st[TILE_F];

    const int tid = threadIdx.x;
    const int base_cell = blockIdx.x * TILE;
    const int valid = min(TILE, ncells - base_cell);
    const int nf = valid * D_DIM;

    // ---- coalesced global -> LDS stage (float4) ----
    const size_t base_f = (size_t)base_cell * D_DIM;  // multiple of 5760 -> 16B aligned
    const float4* p4 = (const float4*)(pred + base_f);
    const float4* t4 = (const float4*)(targ + base_f);
    float4* sp4 = (float4*)sp;
    float4* st4 = (float4*)st;
    const int nf4 = nf >> 2;
    for (int i = tid; i < nf4; i += 256) {
        sp4[i] = p4[i];
        st4[i] = t4[i];
    }
    // scalar tail (only on a ragged last tile)
    for (int i = (nf4 << 2) + tid; i < nf; i += 256) {
        sp[i] = pred[base_f + i];
        st[i] = targ[base_f + i];
    }
    __syncthreads();

    // ---- compute: thread = (cell 0..63, group 0..3) ----
    const int cell = tid & 63;
    const int g = tid >> 6;
    float v_obj = 0.0f, v_coord = 0.0f, v_conf = 0.0f, v_cls = 0.0f;

    if (cell < valid) {
        const float* cp = sp + cell * D_DIM;
        const float* ct = st + cell * D_DIM;
        const float2* cp2 = (const float2*)cp;  // cell*360 B -> 8B aligned
        const float2* ct2 = (const float2*)ct;

        float objf = (ct[4] == 1.0f) ? 1.0f : 0.0f;

        // class partial: elements [10+20g, 30+20g) == float2 idx [5+10g, 15+10g)
        float cls = 0.0f;
        const int s2 = 5 + 10 * g;
        #pragma unroll
        for (int j = 0; j < 10; ++j) {
            float2 p = cp2[s2 + j];
            float2 t = ct2[s2 + j];
            float dx = p.x - t.x;
            float dy = p.y - t.y;
            cls = fmaf(dx, dx, cls);
            cls = fmaf(dy, dy, cls);
        }
        v_cls = cls * (1.0f / (float)NUM_CLASSES) * objf;

        if (g == 0) {
            const int gcell = base_cell + cell;
            const int gxy = gcell % (GRID_S * GRID_S);
            const float gy = (float)(gxy / GRID_S);
            const float gx = (float)(gxy % GRID_S);

            float b1x = cp[0], b1y = cp[1], b1w = cp[2], b1h = cp[3], b1c = cp[4];
            float b2x = cp[5], b2y = cp[6], b2w = cp[7], b2h = cp[8], b2c = cp[9];
            float tbx = ct[0], tby = ct[1], tbw = ct[2], tbh = ct[3];

            const float invS = 1.0f / (float)GRID_S;
            float c1x = (gx + b1x) * invS, c1y = (gy + b1y) * invS;
            float c2x = (gx + b2x) * invS, c2y = (gy + b2y) * invS;
            float ctx = (gx + tbx) * invS, cty = (gy + tby) * invS;

            float iou1 = iou_img(c1x, c1y, b1w, b1h, ctx, cty, tbw, tbh);
            float iou2 = iou_img(c2x, c2y, b2w, b2h, ctx, cty, tbw, tbh);
            bool resp1 = iou1 > iou2;

            float bx = resp1 ? b1x : b2x;
            float by = resp1 ? b1y : b2y;
            float bw = resp1 ? b1w : b2w;
            float bh = resp1 ? b1h : b2h;
            float bc = resp1 ? b1c : b2c;

            bool obj = (objf == 1.0f);

            float ddx = bx - tbx, ddy = by - tby;
            float dxy2 = ddx * ddx + ddy * ddy;
            float swpw = sqrtf(fmaxf(bw, EPS_SQRT));
            float swph = sqrtf(fmaxf(bh, EPS_SQRT));
            float swtw = sqrtf(fmaxf(tbw, EPS_SQRT));
            float swth = sqrtf(fmaxf(tbh, EPS_SQRT));
            float dw = swpw - swtw, dh = swph - swth;
            float dwh2 = dw * dw + dh * dh;
            float coord = 0.5f * dxy2 + 0.5f * dwh2;

            float dco = bc - 1.0f;
            float conf_obj = dco * dco;
            float conf_noobj = LAMBDA_NOOBJ * (b1c * b1c + b2c * b2c);

            v_obj = objf;
            v_coord = coord * objf;
            v_conf = obj ? conf_obj : conf_noobj;
        }
    }

    // ---- wave-64 reduction ----
    #pragma unroll
    for (int off = 32; off > 0; off >>= 1) {
        v_obj   += __shfl_down(v_obj, off, 64);
        v_coord += __shfl_down(v_coord, off, 64);
        v_conf  += __shfl_down(v_conf, off, 64);
        v_cls   += __shfl_down(v_cls, off, 64);
    }

    __shared__ float red[4][4];  // [wave][quantity]
    const int lane = tid & 63;
    const int wid = tid >> 6;
    if (lane == 0) {
        red[wid][0] = v_obj;
        red[wid][1] = v_coord;
        red[wid][2] = v_conf;
        red[wid][3] = v_cls;
    }
    __syncthreads();
    if (tid < 4) {
        float s = red[0][tid] + red[1][tid] + red[2][tid] + red[3][tid];
        atomicAdd(ws + tid, s);
    }
}

__global__ void yolo_final_kernel(const float* __restrict__ ws,
                                  float* __restrict__ out, int ncells) {
    float n_obj = ws[0];
    float coord = ws[1];
    float conf = ws[2];
    float cls = ws[3];
    float n_cells = (float)ncells;
    float conf_count = n_obj + 2.0f * (n_cells - n_obj);
    float denom = fmaxf(n_obj, 1.0f);
    out[0] = LAMBDA_COORD * coord / denom + conf / fmaxf(conf_count, 1.0f) + cls / denom;
}

extern "C" void kernel_launch(void* const* d_in, const int* in_sizes, int n_in,
                              void* d_out, int out_size, void* d_ws, size_t ws_size,
                              hipStream_t stream) {
    const float* pred = (const float*)d_in[0];
    const float* targ = (const float*)d_in[1];
    float* ws = (float*)d_ws;
    float* out = (float*)d_out;

    const int ncells = in_sizes[0] / D_DIM;  // B * S * S
    const int ntiles = (ncells + TILE - 1) / TILE;

    hipMemsetAsync(ws, 0, 4 * sizeof(float), stream);
    yolo_cell_kernel<<<ntiles, 256, 0, stream>>>(pred, targ, ws, ncells);
    yolo_final_kernel<<<1, 1, 0, stream>>>(ws, out, ncells);
}

// Round 3
// 158.401 us; speedup vs baseline: 1.2226x; 1.1223x over previous
//
#include <hip/hip_runtime.h>

#define GRID_S 7
#define NUM_CLASSES 80
#define D_DIM 90
#define LAMBDA_COORD 5.0f
#define LAMBDA_NOOBJ 0.5f
#define EPS_IOU 1e-6f
#define EPS_SQRT 1e-6f

#define TILE 64
#define TILE_F (TILE * D_DIM)     // 5760 floats per array
#define TILE_F4 (TILE_F / 4)      // 1440 float4

__device__ __forceinline__ void async_ld16(const float4* g, float4* l) {
    __builtin_amdgcn_global_load_lds(
        (const __attribute__((address_space(1))) void*)g,
        (__attribute__((address_space(3))) void*)l,
        16, 0, 0);
}

__device__ __forceinline__ float iou_img(float cx1, float cy1, float w1, float h1,
                                         float cx2, float cy2, float w2, float h2) {
    float ixmin = fmaxf(cx1 - w1 * 0.5f, cx2 - w2 * 0.5f);
    float iymin = fmaxf(cy1 - h1 * 0.5f, cy2 - h2 * 0.5f);
    float ixmax = fminf(cx1 + w1 * 0.5f, cx2 + w2 * 0.5f);
    float iymax = fminf(cy1 + h1 * 0.5f, cy2 + h2 * 0.5f);
    float iw = fmaxf(ixmax - ixmin, 0.0f);
    float ih = fmaxf(iymax - iymin, 0.0f);
    float inter = iw * ih;
    float uni = w1 * h1 + w2 * h2 - inter;
    return inter / (uni + EPS_IOU);
}

// part layout: per block, 4 floats: [n_obj, coord, conf, cls]
__global__ __launch_bounds__(256) void yolo_cell_kernel(
        const float* __restrict__ pred, const float* __restrict__ targ,
        float* __restrict__ part, int ncells) {
    __shared__ float sp[TILE_F];
    __shared__ float st[TILE_F];

    const int tid = threadIdx.x;
    const int base_cell = blockIdx.x * TILE;
    const int valid = min(TILE, ncells - base_cell);
    const int nf = valid * D_DIM;
    const int nf4 = nf >> 2;

    // ---- async global -> LDS stage (global_load_lds, width 16) ----
    const size_t base_f = (size_t)base_cell * D_DIM;  // multiple of 5760 -> 16B aligned
    const float4* p4 = (const float4*)(pred + base_f);
    const float4* t4 = (const float4*)(targ + base_f);
    float4* sp4 = (float4*)sp;
    float4* st4 = (float4*)st;
    for (int i = tid; i < nf4; i += 256) async_ld16(p4 + i, sp4 + i);
    for (int i = tid; i < nf4; i += 256) async_ld16(t4 + i, st4 + i);
    // scalar tail (only possible on a ragged last tile)
    for (int i = (nf4 << 2) + tid; i < nf; i += 256) {
        sp[i] = pred[base_f + i];
        st[i] = targ[base_f + i];
    }
    __syncthreads();

    // ---- compute: thread = (cell 0..63, group 0..3) ----
    const int cell = tid & 63;
    const int g = tid >> 6;
    float v_obj = 0.0f, v_coord = 0.0f, v_conf = 0.0f, v_cls = 0.0f;

    if (cell < valid) {
        const float* cp = sp + cell * D_DIM;
        const float* ct = st + cell * D_DIM;
        const float2* cp2 = (const float2*)cp;
        const float2* ct2 = (const float2*)ct;

        float objf = (ct[4] == 1.0f) ? 1.0f : 0.0f;

        // class partial: elements [10+20g, 30+20g) == float2 idx [5+10g, 15+10g)
        float cls = 0.0f;
        const int s2 = 5 + 10 * g;
        #pragma unroll
        for (int j = 0; j < 10; ++j) {
            float2 p = cp2[s2 + j];
            float2 t = ct2[s2 + j];
            float dx = p.x - t.x;
            float dy = p.y - t.y;
            cls = fmaf(dx, dx, cls);
            cls = fmaf(dy, dy, cls);
        }
        v_cls = cls * (1.0f / (float)NUM_CLASSES) * objf;

        if (g == 0) {
            const int gcell = base_cell + cell;
            const int gxy = gcell % (GRID_S * GRID_S);
            const float gy = (float)(gxy / GRID_S);
            const float gx = (float)(gxy % GRID_S);

            float b1x = cp[0], b1y = cp[1], b1w = cp[2], b1h = cp[3], b1c = cp[4];
            float b2x = cp[5], b2y = cp[6], b2w = cp[7], b2h = cp[8], b2c = cp[9];
            float tbx = ct[0], tby = ct[1], tbw = ct[2], tbh = ct[3];

            const float invS = 1.0f / (float)GRID_S;
            float c1x = (gx + b1x) * invS, c1y = (gy + b1y) * invS;
            float c2x = (gx + b2x) * invS, c2y = (gy + b2y) * invS;
            float ctx = (gx + tbx) * invS, cty = (gy + tby) * invS;

            float iou1 = iou_img(c1x, c1y, b1w, b1h, ctx, cty, tbw, tbh);
            float iou2 = iou_img(c2x, c2y, b2w, b2h, ctx, cty, tbw, tbh);
            bool resp1 = iou1 > iou2;

            float bx = resp1 ? b1x : b2x;
            float by = resp1 ? b1y : b2y;
            float bw = resp1 ? b1w : b2w;
            float bh = resp1 ? b1h : b2h;
            float bc = resp1 ? b1c : b2c;

            bool obj = (objf == 1.0f);

            float ddx = bx - tbx, ddy = by - tby;
            float dxy2 = ddx * ddx + ddy * ddy;
            float swpw = sqrtf(fmaxf(bw, EPS_SQRT));
            float swph = sqrtf(fmaxf(bh, EPS_SQRT));
            float swtw = sqrtf(fmaxf(tbw, EPS_SQRT));
            float swth = sqrtf(fmaxf(tbh, EPS_SQRT));
            float dw = swpw - swtw, dh = swph - swth;
            float dwh2 = dw * dw + dh * dh;
            float coord = 0.5f * dxy2 + 0.5f * dwh2;

            float dco = bc - 1.0f;
            float conf_obj = dco * dco;
            float conf_noobj = LAMBDA_NOOBJ * (b1c * b1c + b2c * b2c);

            v_obj = objf;
            v_coord = coord * objf;
            v_conf = obj ? conf_obj : conf_noobj;
        }
    }

    // ---- wave-64 reduction ----
    #pragma unroll
    for (int off = 32; off > 0; off >>= 1) {
        v_obj   += __shfl_down(v_obj, off, 64);
        v_coord += __shfl_down(v_coord, off, 64);
        v_conf  += __shfl_down(v_conf, off, 64);
        v_cls   += __shfl_down(v_cls, off, 64);
    }

    __shared__ float red[4][4];  // [wave][quantity]
    const int lane = tid & 63;
    const int wid = tid >> 6;
    if (lane == 0) {
        red[wid][0] = v_obj;
        red[wid][1] = v_coord;
        red[wid][2] = v_conf;
        red[wid][3] = v_cls;
    }
    __syncthreads();
    if (tid < 4) {
        // plain store to a per-block slot — no atomics, no contention
        float s = red[0][tid] + red[1][tid] + red[2][tid] + red[3][tid];
        part[(size_t)blockIdx.x * 4 + tid] = s;
    }
}

__global__ __launch_bounds__(1024) void yolo_final_kernel(
        const float* __restrict__ part, float* __restrict__ out,
        int nblocks, int ncells) {
    const int tid = threadIdx.x;
    float a0 = 0.0f, a1 = 0.0f, a2 = 0.0f, a3 = 0.0f;
    const float4* p4 = (const float4*)part;
    for (int b = tid; b < nblocks; b += 1024) {
        float4 v = p4[b];
        a0 += v.x; a1 += v.y; a2 += v.z; a3 += v.w;
    }
    #pragma unroll
    for (int off = 32; off > 0; off >>= 1) {
        a0 += __shfl_down(a0, off, 64);
        a1 += __shfl_down(a1, off, 64);
        a2 += __shfl_down(a2, off, 64);
        a3 += __shfl_down(a3, off, 64);
    }
    __shared__ float red[16][4];
    const int wid = tid >> 6;
    if ((tid & 63) == 0) {
        red[wid][0] = a0; red[wid][1] = a1; red[wid][2] = a2; red[wid][3] = a3;
    }
    __syncthreads();
    if (tid == 0) {
        float n_obj = 0.0f, coord = 0.0f, conf = 0.0f, cls = 0.0f;
        #pragma unroll
        for (int w = 0; w < 16; ++w) {
            n_obj += red[w][0]; coord += red[w][1];
            conf  += red[w][2]; cls   += red[w][3];
        }
        float n_cells = (float)ncells;
        float conf_count = n_obj + 2.0f * (n_cells - n_obj);
        float denom = fmaxf(n_obj, 1.0f);
        out[0] = LAMBDA_COORD * coord / denom + conf / fmaxf(conf_count, 1.0f) + cls / denom;
    }
}

extern "C" void kernel_launch(void* const* d_in, const int* in_sizes, int n_in,
                              void* d_out, int out_size, void* d_ws, size_t ws_size,
                              hipStream_t stream) {
    const float* pred = (const float*)d_in[0];
    const float* targ = (const float*)d_in[1];
    float* part = (float*)d_ws;
    float* out = (float*)d_out;

    const int ncells = in_sizes[0] / D_DIM;  // B * S * S
    const int ntiles = (ncells + TILE - 1) / TILE;

    yolo_cell_kernel<<<ntiles, 256, 0, stream>>>(pred, targ, part, ncells);
    yolo_final_kernel<<<1, 1024, 0, stream>>>(part, out, ntiles, ncells);
}